// Round 1
// baseline (634.789 us; speedup 1.0000x reference)
//
#include <hip/hip_runtime.h>
#include <hip/hip_bf16.h>
#include <math.h>
#include <stdint.h>

// DiverseSiblingsSearch:
//   lprobs (128,5,50257) f32, scores (128,5,10) f32, step=10
//   lp = lprobs + scores[:,:,step-1,None]
//   s,idx = top_k(lp, 10) per (b,beam) over vocab      [stage 1]
//   s -= arange(1..10)*0.5
//   final top_k over beam*10=50 candidates per b       [stage 2]
// Outputs concat (all written as float32 values): scores[1280] | indices[1280] | beams[1280]

#define BS   256
#define KK   10
#define BEAM 5

__global__ __launch_bounds__(BS) void dss_stage1(
    const float* __restrict__ lprobs,
    const float* __restrict__ scores,
    const int*   __restrict__ step_ptr,
    int vocab, int sdim,
    float* __restrict__ ws_val,
    int*   __restrict__ ws_idx)
{
    const int row = blockIdx.x;        // b*BEAM + beam, 0..639
    const int tid = threadIdx.x;
    const int step = step_ptr[0];
    const float bias = scores[(size_t)row * sdim + (step - 1)];
    const float* rp = lprobs + (size_t)row * vocab;

    // per-thread exact top-K under total order (value desc, index asc)
    float val[KK];
    int   idx[KK];
#pragma unroll
    for (int j = 0; j < KK; ++j) { val[j] = -INFINITY; idx[j] = 0x7fffffff; }

    auto consider = [&](float x, int i) {
        float v = x + bias;
        bool beats_last = (v > val[KK-1]) || (v == val[KK-1] && i < idx[KK-1]);
        if (beats_last) {
#pragma unroll
            for (int j = KK - 1; j >= 1; --j) {
                bool bm1 = (v > val[j-1]) || (v == val[j-1] && i < idx[j-1]);
                bool bj  = (v > val[j])   || (v == val[j]   && i < idx[j]);
                val[j] = bm1 ? val[j-1] : (bj ? v : val[j]);
                idx[j] = bm1 ? idx[j-1] : (bj ? i : idx[j]);
            }
            bool b0 = (v > val[0]) || (v == val[0] && i < idx[0]);
            if (b0) { val[0] = v; idx[0] = i; }
        }
    };

    // alignment prologue so the float4 body is 16B-aligned (rows are odd-length)
    int pre = (4 - (int)(((uintptr_t)rp >> 2) & 3)) & 3;
    if (pre > vocab) pre = vocab;
    if (tid < pre) consider(rp[tid], tid);

    const float4* p4 = (const float4*)(rp + pre);
    const int nvec = (vocab - pre) >> 2;
    for (int t = tid; t < nvec; t += BS) {
        float4 x = p4[t];
        int base = pre + 4 * t;
        consider(x.x, base + 0);
        consider(x.y, base + 1);
        consider(x.z, base + 2);
        consider(x.w, base + 3);
    }
    int done = pre + 4 * nvec;
    int rem = vocab - done;
    if (tid < rem) consider(rp[done + tid], done + tid);

    // block reduction: LDS merge tree of sorted 10-lists
    __shared__ float sval[BS * KK];
    __shared__ int   sidx[BS * KK];
#pragma unroll
    for (int j = 0; j < KK; ++j) { sval[tid * KK + j] = val[j]; sidx[tid * KK + j] = idx[j]; }
    __syncthreads();

    for (int off = BS / 2; off >= 1; off >>= 1) {
        if (tid < off) {
            const int pa = tid * KK, pb = (tid + off) * KK;
            float mv[KK]; int mi[KK];
            int ia = 0, ib = 0;
#pragma unroll
            for (int j = 0; j < KK; ++j) {
                float va = sval[pa + ia], vb = sval[pb + ib];
                int   xa = sidx[pa + ia], xb = sidx[pb + ib];
                bool takeA = (va > vb) || (va == vb && xa <= xb);
                if (takeA) { mv[j] = va; mi[j] = xa; ++ia; }
                else       { mv[j] = vb; mi[j] = xb; ++ib; }
            }
#pragma unroll
            for (int j = 0; j < KK; ++j) { sval[pa + j] = mv[j]; sidx[pa + j] = mi[j]; }
        }
        __syncthreads();
    }

    if (tid < KK) {
        ws_val[row * KK + tid] = sval[tid];
        ws_idx[row * KK + tid] = sidx[tid];
    }
}

// one 64-lane wave per batch row; lanes 0..49 hold the penalized candidates
__global__ __launch_bounds__(64) void dss_stage2(
    const float* __restrict__ ws_val,
    const int*   __restrict__ ws_idx,
    float* __restrict__ out, int bsz)
{
    const int b = blockIdx.x;
    const int lane = threadIdx.x;

    float v = -INFINITY;
    int   vidx = 0;
    if (lane < BEAM * KK) {
        int beam = lane / KK;
        int r    = lane % KK;
        int o    = (b * BEAM + beam) * KK + r;
        v    = ws_val[o] - 0.5f * (float)(r + 1);   // sibling rank penalty
        vidx = ws_idx[o];
    }

    float* out_scores  = out;
    float* out_indices = out + (size_t)bsz * KK;
    float* out_beams   = out + 2 * (size_t)bsz * KK;

    for (int o = 0; o < KK; ++o) {
        float rv = v; int rp = lane;
        // butterfly argmax, tie -> lowest flat position (matches jax top_k)
#pragma unroll
        for (int off = 32; off >= 1; off >>= 1) {
            float ov = __shfl_xor(rv, off);
            int   op = __shfl_xor(rp, off);
            if (ov > rv || (ov == rv && op < rp)) { rv = ov; rp = op; }
        }
        int widx = __shfl(vidx, rp);   // winner's vocab id
        if (lane == 0) {
            out_scores [b * KK + o] = rv;
            out_indices[b * KK + o] = (float)widx;
            out_beams  [b * KK + o] = (float)(rp / KK);
        }
        if (lane == rp) v = -INFINITY; // remove winner
    }
}

extern "C" void kernel_launch(void* const* d_in, const int* in_sizes, int n_in,
                              void* d_out, int out_size, void* d_ws, size_t ws_size,
                              hipStream_t stream)
{
    const float* lprobs = (const float*)d_in[0];
    const float* scores = (const float*)d_in[1];
    const int*   step   = (const int*)d_in[2];

    const int bsz   = 128;
    const int rows  = bsz * BEAM;                 // 640
    const int vocab = in_sizes[0] / rows;         // 50257
    const int sdim  = in_sizes[1] / rows;         // 10

    float* ws_val = (float*)d_ws;
    int*   ws_idx = (int*)((char*)d_ws + (size_t)rows * KK * sizeof(float));

    dss_stage1<<<rows, BS, 0, stream>>>(lprobs, scores, step, vocab, sdim, ws_val, ws_idx);
    dss_stage2<<<bsz, 64, 0, stream>>>(ws_val, ws_idx, (float*)d_out, bsz);
}

// Round 2
// 225.800 us; speedup vs baseline: 2.8113x; 2.8113x over previous
//
#include <hip/hip_runtime.h>
#include <hip/hip_bf16.h>
#include <math.h>
#include <stdint.h>

// DiverseSiblingsSearch:
//   lprobs (128,5,50257) f32, scores (128,5,10) f32, step=10
//   stage1: per (b,beam) row, exact top-10 of lprobs+bias over vocab
//           (threshold-filter algorithm: pass1 = per-thread max -> tau = 10th
//            largest of the 256 thread maxes (a valid lower bound on the row's
//            10th-largest); pass2 = filter x>=tau (survivors provably <=1970),
//            merge survivors. Bias is a per-row constant -> deferred to output.)
//   stage2: per b, top-10 of the 50 rank-penalized candidates
// Outputs concat as float32 values: scores[1280] | indices[1280] | beams[1280]

#define BS   256
#define KK   10
#define BEAM 5
#define CAP  2048   // worst-case survivors: 10 threads * ceil(50257/256) = 1970

typedef unsigned long long u64;

// monotone float <-> uint map (no NaNs in log_softmax output)
__device__ __forceinline__ uint32_t ford(float x) {
    uint32_t u = __float_as_uint(x);
    return (u & 0x80000000u) ? ~u : (u | 0x80000000u);
}
__device__ __forceinline__ float funord(uint32_t u) {
    return __uint_as_float((u & 0x80000000u) ? (u & 0x7fffffffu) : ~u);
}

// block-wide merge tree over BS sorted-descending 10-lists in LDS.
// result: skey[0..9] = top-10 keys, sorted descending.
__device__ __forceinline__ void merge_tree(u64* skey, int tid) {
    for (int off = BS / 2; off >= 1; off >>= 1) {
        if (tid < off) {
            const int pa = tid * KK, pb = (tid + off) * KK;
            u64 mk[KK];
            int ia = 0, ib = 0;
#pragma unroll
            for (int j = 0; j < KK; ++j) {
                u64 ka = skey[pa + ia], kb = skey[pb + ib];
                bool takeA = (ka >= kb);
                mk[j] = takeA ? ka : kb;
                if (takeA) ++ia; else ++ib;
            }
#pragma unroll
            for (int j = 0; j < KK; ++j) skey[pa + j] = mk[j];
        }
        __syncthreads();
    }
}

__global__ __launch_bounds__(BS) void dss_stage1(
    const float* __restrict__ lprobs,
    const float* __restrict__ scores,
    const int*   __restrict__ step_ptr,
    int vocab, int sdim,
    float* __restrict__ ws_val,
    int*   __restrict__ ws_idx)
{
    const int row = blockIdx.x;        // b*BEAM + beam, 0..639
    const int tid = threadIdx.x;
    const int step = step_ptr[0];
    const float bias = scores[(size_t)row * sdim + (step - 1)];
    const float* rp = lprobs + (size_t)row * vocab;

    __shared__ u64  cand[CAP];
    __shared__ u64  skey[BS * KK];
    __shared__ int  cnt;
    __shared__ float s_tau;

    // row start misaligned by row%4 dwords (vocab odd); 16B-align the body
    int pre = (4 - (int)(((uintptr_t)rp >> 2) & 3)) & 3;
    if (pre > vocab) pre = vocab;
    const float4* p4 = (const float4*)(rp + pre);
    const int nvec = (vocab - pre) >> 2;
    const int done = pre + 4 * nvec;
    const int rem  = vocab - done;

    // ---------------- pass 1: per-thread raw max (no bias, no divergence)
    float m = -INFINITY;
    if (tid < pre) m = rp[tid];
#pragma unroll 4
    for (int t = tid; t < nvec; t += BS) {
        float4 x = p4[t];
        m = fmaxf(m, fmaxf(fmaxf(x.x, x.y), fmaxf(x.z, x.w)));
    }
    if (tid < rem) m = fmaxf(m, rp[done + tid]);

    // ---------------- phase A: tau = 10th largest of the 256 thread maxes
    {
        u64 key[KK];
        key[0] = ((u64)ford(m) << 32) | (uint32_t)~tid;   // low bits only need distinctness
#pragma unroll
        for (int j = 1; j < KK; ++j) key[j] = 0;
#pragma unroll
        for (int j = 0; j < KK; ++j) skey[tid * KK + j] = key[j];
    }
    if (tid == 0) cnt = 0;
    __syncthreads();
    merge_tree(skey, tid);
    if (tid == 0) s_tau = funord((uint32_t)(skey[9] >> 32));
    __syncthreads();
    const float tau = s_tau;

    // ---------------- pass 2: filter x >= tau, append survivors to LDS
    auto app = [&](float x, int i) {
        if (x >= tau) {
            int p = atomicAdd(&cnt, 1);
            if (p < CAP) cand[p] = ((u64)ford(x) << 32) | (uint32_t)~i;
        }
    };
    if (tid < pre) app(rp[tid], tid);
#pragma unroll 4
    for (int t = tid; t < nvec; t += BS) {
        float4 x = p4[t];
        int base = pre + 4 * t;
        if (x.x >= tau) app(x.x, base + 0);
        if (x.y >= tau) app(x.y, base + 1);
        if (x.z >= tau) app(x.z, base + 2);
        if (x.w >= tau) app(x.w, base + 3);
    }
    if (tid < rem) app(rp[done + tid], done + tid);
    __syncthreads();

    // ---------------- phase B: top-10 of survivors (count >= 10 guaranteed)
    const int n = (cnt < CAP) ? cnt : CAP;
    {
        u64 key[KK];
#pragma unroll
        for (int j = 0; j < KK; ++j) key[j] = 0;
        for (int i = tid; i < n; i += BS) {
            u64 k = cand[i];
            if (k > key[KK - 1]) {
#pragma unroll
                for (int j = KK - 1; j >= 1; --j)
                    key[j] = (k > key[j - 1]) ? key[j - 1] : ((k > key[j]) ? k : key[j]);
                if (k > key[0]) key[0] = k;
            }
        }
#pragma unroll
        for (int j = 0; j < KK; ++j) skey[tid * KK + j] = key[j];
    }
    __syncthreads();
    merge_tree(skey, tid);

    if (tid < KK) {
        u64 k = skey[tid];
        ws_val[row * KK + tid] = funord((uint32_t)(k >> 32)) + bias;
        ws_idx[row * KK + tid] = (int)~(uint32_t)k;
    }
}

// one 64-lane wave per batch row; lanes 0..49 hold the penalized candidates
__global__ __launch_bounds__(64) void dss_stage2(
    const float* __restrict__ ws_val,
    const int*   __restrict__ ws_idx,
    float* __restrict__ out, int bsz)
{
    const int b = blockIdx.x;
    const int lane = threadIdx.x;

    float v = -INFINITY;
    int   vidx = 0;
    if (lane < BEAM * KK) {
        int beam = lane / KK;
        int r    = lane % KK;
        int o    = (b * BEAM + beam) * KK + r;
        v    = ws_val[o] - 0.5f * (float)(r + 1);   // sibling rank penalty
        vidx = ws_idx[o];
    }

    float* out_scores  = out;
    float* out_indices = out + (size_t)bsz * KK;
    float* out_beams   = out + 2 * (size_t)bsz * KK;

    for (int o = 0; o < KK; ++o) {
        float rv = v; int rp = lane;
        // butterfly argmax, tie -> lowest flat position (matches jax top_k)
#pragma unroll
        for (int off = 32; off >= 1; off >>= 1) {
            float ov = __shfl_xor(rv, off);
            int   op = __shfl_xor(rp, off);
            if (ov > rv || (ov == rv && op < rp)) { rv = ov; rp = op; }
        }
        int widx = __shfl(vidx, rp);   // winner's vocab id
        if (lane == 0) {
            out_scores [b * KK + o] = rv;
            out_indices[b * KK + o] = (float)widx;
            out_beams  [b * KK + o] = (float)(rp / KK);
        }
        if (lane == rp) v = -INFINITY; // remove winner
    }
}

extern "C" void kernel_launch(void* const* d_in, const int* in_sizes, int n_in,
                              void* d_out, int out_size, void* d_ws, size_t ws_size,
                              hipStream_t stream)
{
    const float* lprobs = (const float*)d_in[0];
    const float* scores = (const float*)d_in[1];
    const int*   step   = (const int*)d_in[2];

    const int bsz   = 128;
    const int rows  = bsz * BEAM;                 // 640
    const int vocab = in_sizes[0] / rows;         // 50257
    const int sdim  = in_sizes[1] / rows;         // 10

    float* ws_val = (float*)d_ws;
    int*   ws_idx = (int*)((char*)d_ws + (size_t)rows * KK * sizeof(float));

    dss_stage1<<<rows, BS, 0, stream>>>(lprobs, scores, step, vocab, sdim, ws_val, ws_idx);
    dss_stage2<<<bsz, 64, 0, stream>>>(ws_val, ws_idx, (float*)d_out, bsz);
}